// Round 3
// baseline (1457.001 us; speedup 1.0000x reference)
//
#include <hip/hip_runtime.h>
#include <math.h>

static constexpr int B_ = 16;
static constexpr int N_ = 1024;
static constexpr int K_ = 20;

// ---------------- per-point squared norm ----------------
template<int C>
__global__ __launch_bounds__(256) void xx_kernel(const float* __restrict__ h,
                                                 float* __restrict__ xx) {
  int i = blockIdx.x * 256 + threadIdx.x;
  if (i >= B_ * N_) return;
  int b = i >> 10, n = i & 1023;
  const float* hb = h + (size_t)b * C * N_ + n;
  float s = 0.f;
  #pragma unroll 4
  for (int c = 0; c < C; ++c) { float v = hb[(size_t)c * N_]; s = fmaf(v, v, s); }
  xx[i] = s;
}

// ---------------- fused distance + top-20 selection (register-resident) -------
// block = (b, 16 rows), 4 waves x 4 rows. Lane holds 16 distance values in regs
// (col = ch*128 + 2*lane + j, t = 2*ch + j). ALL private-array indices are
// compile-time static (rule #20: runtime index -> scratch, the R2 spill bug).
template<int C>
__global__ __launch_bounds__(256) void knn_kernel(const float* __restrict__ h,
                                                  const float* __restrict__ xx,
                                                  int* __restrict__ idxg) {
  constexpr int CC = (C < 64) ? C : 64;
  __shared__ float xm_s[CC][128];      // <= 32 KB
  __shared__ float xn_s[C][16];        // <= 8 KB
  const int b  = blockIdx.y;
  const int n0 = blockIdx.x * 16;
  const int tid = threadIdx.x;
  const int lane = tid & 63;
  const int wv   = tid >> 6;
  const int rb   = wv * 4;
  const float* hb = h + (size_t)b * C * N_;
  const float* xxb = xx + b * N_;

  for (int i = tid; i < C * 16; i += 256) {
    int c = i >> 4, r = i & 15;
    xn_s[c][r] = hb[(size_t)c * N_ + n0 + r];
  }
  float xxn[4];
  #pragma unroll
  for (int rr = 0; rr < 4; ++rr) xxn[rr] = xxb[n0 + rb + rr];

  float val[4][16];   // val[row][t], t = 2*ch + j, col = ch*128 + 2*lane + j
  #pragma unroll
  for (int ch = 0; ch < 8; ++ch) {          // FULLY unrolled: static val indices
    const int m0 = ch * 128;
    float acc0[4] = {0.f, 0.f, 0.f, 0.f};
    float acc1[4] = {0.f, 0.f, 0.f, 0.f};
    #pragma unroll
    for (int cc0 = 0; cc0 < C; cc0 += CC) {
      __syncthreads();                       // protect previous chunk reads (+xn on first)
      #pragma unroll 4
      for (int i = tid; i < CC * 128; i += 256) {
        int c = i >> 7, mm = i & 127;
        xm_s[c][mm] = hb[(size_t)(cc0 + c) * N_ + m0 + mm];
      }
      __syncthreads();
      #pragma unroll 4
      for (int c = 0; c < CC; ++c) {
        float2 xm2 = *(const float2*)&xm_s[c][2 * lane];          // ds_read_b64
        float4 xn4 = *(const float4*)&xn_s[cc0 + c][rb];          // broadcast b128
        float xnv[4] = {xn4.x, xn4.y, xn4.z, xn4.w};
        #pragma unroll
        for (int rr = 0; rr < 4; ++rr) {
          acc0[rr] = fmaf(xnv[rr], xm2.x, acc0[rr]);
          acc1[rr] = fmaf(xnv[rr], xm2.y, acc1[rr]);
        }
      }
    }
    // neg_d2 = -((xx_n - 2*inner) + xx_m)  (same fp32 rounding as reference path)
    float2 xxm2 = *(const float2*)&xxb[m0 + 2 * lane];
    #pragma unroll
    for (int rr = 0; rr < 4; ++rr) {
      val[rr][2 * ch]     = -(fmaf(-2.f, acc0[rr], xxn[rr]) + xxm2.x);
      val[rr][2 * ch + 1] = -(fmaf(-2.f, acc1[rr], xxn[rr]) + xxm2.y);
    }
  }

  // -------- selection: 2 pairs of rows, chains interleaved; in-place on val ----
  #pragma unroll
  for (int pr = 0; pr < 2; ++pr) {
    float (&va)[16] = val[2 * pr];
    float (&vb)[16] = val[2 * pr + 1];
    unsigned colA[16], colB[16];
    #pragma unroll
    for (int t = 0; t < 16; ++t) {
      unsigned col = (unsigned)((t >> 1) * 128 + 2 * lane + (t & 1));
      colA[t] = col; colB[t] = col;
    }
    // bitonic sort, descending by (value, then lowest col first on ties)
    #pragma unroll
    for (int k = 2; k <= 16; k <<= 1) {
      #pragma unroll
      for (int j = k >> 1; j > 0; j >>= 1) {
        #pragma unroll
        for (int i = 0; i < 16; ++i) {
          int l = i ^ j;
          if (l > i) {
            bool up = (i & k) == 0;   // up: keep larger at i
            {
              bool gt = (va[l] > va[i]) || (va[l] == va[i] && colA[l] < colA[i]);
              bool cnd = up ? gt : !gt;
              float tv = va[i]; unsigned tc = colA[i];
              va[i] = cnd ? va[l] : tv;   colA[i] = cnd ? colA[l] : tc;
              va[l] = cnd ? tv : va[l];   colA[l] = cnd ? tc : colA[l];
            }
            {
              bool gt = (vb[l] > vb[i]) || (vb[l] == vb[i] && colB[l] < colB[i]);
              bool cnd = up ? gt : !gt;
              float tv = vb[i]; unsigned tc = colB[i];
              vb[i] = cnd ? vb[l] : tv;   colB[i] = cnd ? colB[l] : tc;
              vb[l] = cnd ? tv : vb[l];   colB[l] = cnd ? tc : colB[l];
            }
          }
        }
      }
    }
    const int outA = (b * N_ + n0 + rb + 2 * pr) * K_;
    const int outB = outA + K_;
    #pragma unroll 1
    for (int it = 0; it < K_; ++it) {
      float bvA = va[0]; unsigned bcA = colA[0];
      float bvB = vb[0]; unsigned bcB = colB[0];
      #pragma unroll
      for (int off = 32; off >= 1; off >>= 1) {
        float ovA = __shfl_xor(bvA, off); unsigned ocA = (unsigned)__shfl_xor((int)bcA, off);
        float ovB = __shfl_xor(bvB, off); unsigned ocB = (unsigned)__shfl_xor((int)bcB, off);
        bool tA = (ovA > bvA) || (ovA == bvA && ocA < bcA);
        bvA = tA ? ovA : bvA; bcA = tA ? ocA : bcA;
        bool tB = (ovB > bvB) || (ovB == bvB && ocB < bcB);
        bvB = tB ? ovB : bvB; bcB = tB ? ocB : bcB;
      }
      if (lane == 0) {
        idxg[outA + it] = (int)bcA;
        idxg[outB + it] = (int)bcB;
      }
      if (colA[0] == bcA) {   // winner lane pops its head (exec-masked shift)
        #pragma unroll
        for (int t = 0; t < 15; ++t) { va[t] = va[t + 1]; colA[t] = colA[t + 1]; }
        va[15] = -3.4e38f; colA[15] = 0xFFFFFFFFu;
      }
      if (colB[0] == bcB) {
        #pragma unroll
        for (int t = 0; t < 15; ++t) { vb[t] = vb[t + 1]; colB[t] = colB[t + 1]; }
        vb[15] = -3.4e38f; colB[15] = 0xFFFFFFFFu;
      }
    }
  }
}

// ---------------- u = W1*h, w = (W2-W1)*h ----------------
// out layout (B, N, CO). grid: x = N/128, y = (CO/64)*2 (even=u, odd=w), z = B
template<int C, int CO>
__global__ __launch_bounds__(256) void gemm_uw_kernel(const float* __restrict__ h,
    const float* __restrict__ W, float* __restrict__ ubuf, float* __restrict__ wbuf) {
  __shared__ float hs[C][128];
  __shared__ float Ws[64][C + 1];          // +1 pad: kill 32-way bank conflict
  const int b  = blockIdx.z;
  const int n0 = blockIdx.x * 128;
  const int which = blockIdx.y & 1;
  const int o0 = (blockIdx.y >> 1) * 64;
  const int tid = threadIdx.x;
  for (int i = tid; i < 64 * C; i += 256) {
    int o = i / C, c = i % C;
    const float* wr = W + (size_t)(o0 + o) * (2 * C);
    float w1 = wr[c];
    Ws[o][c] = which ? (wr[C + c] - w1) : w1;
  }
  const float* hb = h + (size_t)b * C * N_ + n0;
  for (int i = tid; i < C * 128; i += 256) {
    int c = i >> 7, nn = i & 127;
    hs[c][nn] = hb[(size_t)c * N_ + nn];
  }
  __syncthreads();
  const int ob = (tid & 15) * 4;
  const int nb = (tid >> 4) * 8;
  float acc[8][4];
  #pragma unroll
  for (int i = 0; i < 8; ++i)
    #pragma unroll
    for (int j = 0; j < 4; ++j) acc[i][j] = 0.f;
  for (int c = 0; c < C; ++c) {
    float hv[8];
    *(float4*)&hv[0] = *(const float4*)&hs[c][nb];
    *(float4*)&hv[4] = *(const float4*)&hs[c][nb + 4];
    float w0 = Ws[ob][c], w1 = Ws[ob + 1][c], w2 = Ws[ob + 2][c], w3 = Ws[ob + 3][c];
    #pragma unroll
    for (int i = 0; i < 8; ++i) {
      acc[i][0] = fmaf(hv[i], w0, acc[i][0]);
      acc[i][1] = fmaf(hv[i], w1, acc[i][1]);
      acc[i][2] = fmaf(hv[i], w2, acc[i][2]);
      acc[i][3] = fmaf(hv[i], w3, acc[i][3]);
    }
  }
  float* out = (which ? wbuf : ubuf) + ((size_t)(b * N_ + n0 + nb)) * CO + o0 + ob;
  #pragma unroll
  for (int i = 0; i < 8; ++i) {
    float4 v4; v4.x = acc[i][0]; v4.y = acc[i][1]; v4.z = acc[i][2]; v4.w = acc[i][3];
    *(float4*)(out + (size_t)i * CO) = v4;
  }
}

// ---------------- gather pass: per-(o,n) max/min over k + fp64 stats ----------------
template<int CO, int NSPLIT>
__global__ __launch_bounds__(256) void passA_kernel(const float* __restrict__ ubuf,
    const float* __restrict__ wbuf, const int* __restrict__ idxg,
    float* __restrict__ Mx, float* __restrict__ Mn, double* __restrict__ stats) {
  __shared__ float us[N_][32];             // 128 KB, gather reads conflict-free (o fastest)
  const int b = blockIdx.y;
  const int otile = blockIdx.x / NSPLIT;
  const int ns    = blockIdx.x % NSPLIT;
  const int o0 = otile * 32;
  constexpr int NSUB = N_ / NSPLIT;
  const int nstart = ns * NSUB;
  const int tid = threadIdx.x;
  const float* ub = ubuf + (size_t)b * N_ * CO + o0;
  for (int i = tid; i < N_ * 32; i += 256) {
    int n = i >> 5, o = i & 31;
    us[n][o] = ub[(size_t)n * CO + o];
  }
  __syncthreads();
  const int o = tid & 31, ng = tid >> 5;
  double s_y = 0.0, s_y2 = 0.0;
  const size_t bnc = (size_t)b * N_ * CO;
  for (int n = nstart + ng; n < nstart + NSUB; n += 8) {
    const int* ip = idxg + (size_t)(b * N_ + n) * K_;
    int js[20];
    #pragma unroll
    for (int q = 0; q < 5; ++q) {
      int4 t4 = ((const int4*)ip)[q];
      js[q * 4 + 0] = t4.x; js[q * 4 + 1] = t4.y;
      js[q * 4 + 2] = t4.z; js[q * 4 + 3] = t4.w;
    }
    float mx = -3.4e38f, mn = 3.4e38f, s1 = 0.f, s2 = 0.f;
    #pragma unroll
    for (int k = 0; k < 20; ++k) {
      float v = us[js[k]][o];
      mx = fmaxf(mx, v); mn = fminf(mn, v);
      s1 += v; s2 = fmaf(v, v, s2);
    }
    float wvv = wbuf[bnc + (size_t)n * CO + o0 + o];
    s_y  += (double)s1 + 20.0 * (double)wvv;
    s_y2 += (double)s2 + 2.0 * (double)wvv * (double)s1 + 20.0 * (double)wvv * (double)wvv;
    Mx[bnc + (size_t)n * CO + o0 + o] = mx;
    Mn[bnc + (size_t)n * CO + o0 + o] = mn;
  }
  __syncthreads();                          // us dead: reuse as reduction scratch
  double* sc = (double*)&us[0][0];
  sc[(o * 8 + ng) * 2]     = s_y;
  sc[(o * 8 + ng) * 2 + 1] = s_y2;
  __syncthreads();
  if (tid < 32) {
    double a = 0.0, c2 = 0.0;
    #pragma unroll
    for (int g = 0; g < 8; ++g) { a += sc[(tid * 8 + g) * 2]; c2 += sc[(tid * 8 + g) * 2 + 1]; }
    atomicAdd(&stats[(o0 + tid) * 2],     a);
    atomicAdd(&stats[(o0 + tid) * 2 + 1], c2);
  }
}

// ---------------- BN + LeakyReLU + (implicit max_k) + transpose to (B,C,N) ----------------
template<int CO>
__global__ __launch_bounds__(256) void passB_kernel(const float* __restrict__ Mx,
    const float* __restrict__ Mn, const float* __restrict__ wbuf,
    const double* __restrict__ stats, const float* __restrict__ gam,
    const float* __restrict__ bet, float* __restrict__ hout) {
  __shared__ float T[CO][65];
  __shared__ float a_s[CO], c_s[CO];
  const int b = blockIdx.y, n0 = blockIdx.x * 64;
  const int tid = threadIdx.x;
  const double CNT = (double)B_ * N_ * K_;
  for (int oo = tid; oo < CO; oo += 256) {
    double m  = stats[oo * 2] / CNT;
    double vv = stats[oo * 2 + 1] / CNT - m * m;
    float a = gam[oo] * rsqrtf((float)vv + 1e-5f);
    a_s[oo] = a;
    c_s[oo] = bet[oo] - a * (float)m;
  }
  __syncthreads();
  const size_t base = (size_t)(b * N_ + n0) * CO;
  for (int i = tid; i < 64 * CO; i += 256) {
    int nn = i / CO, oo = i % CO;
    float a = a_s[oo];
    size_t off = base + (size_t)nn * CO + oo;
    float selv = (a >= 0.f) ? Mx[off] : Mn[off];    // max_k commutes through monotone BN+LReLU
    float z = fmaf(a, selv + wbuf[off], c_s[oo]);
    T[oo][nn] = (z >= 0.f) ? z : 0.2f * z;
  }
  __syncthreads();
  float* hb = hout + (size_t)b * CO * N_ + n0;
  for (int i = tid; i < 64 * CO; i += 256) {
    int oo = i >> 6, nn = i & 63;
    hb[(size_t)oo * N_ + nn] = T[oo][nn];
  }
}

// ---------------- final layer: BN + LReLU + max over (n,k) ----------------
__global__ __launch_bounds__(256) void final_kernel(const float* __restrict__ Mx,
    const float* __restrict__ Mn, const float* __restrict__ wbuf,
    const double* __restrict__ stats, const float* __restrict__ gam,
    const float* __restrict__ bet, float* __restrict__ out) {
  const int b = blockIdx.x, o = threadIdx.x;   // 256 threads = CO
  const double CNT = (double)B_ * N_ * K_;
  double m  = stats[o * 2] / CNT;
  double vv = stats[o * 2 + 1] / CNT - m * m;
  float a = gam[o] * rsqrtf((float)vv + 1e-5f);
  float c = bet[o] - a * (float)m;
  const float* mp = ((a >= 0.f) ? Mx : Mn) + (size_t)b * N_ * 256 + o;
  const float* wp = wbuf + (size_t)b * N_ * 256 + o;
  float best = -3.4e38f;
  for (int n = 0; n < N_; ++n) {
    float z = fmaf(a, mp[(size_t)n * 256] + wp[(size_t)n * 256], c);
    z = (z >= 0.f) ? z : 0.2f * z;
    best = fmaxf(best, z);
  }
  out[b * 256 + o] = best;
}

__global__ void zero_stats(double* p) {
  int i = blockIdx.x * 256 + threadIdx.x;
  if (i < 2048) p[i] = 0.0;
}

extern "C" void kernel_launch(void* const* d_in, const int* in_sizes, int n_in,
                              void* d_out, int out_size, void* d_ws, size_t ws_size,
                              hipStream_t stream) {
  (void)in_sizes; (void)n_in; (void)out_size; (void)ws_size;
  const float* x  = (const float*)d_in[0];
  const float* W0 = (const float*)d_in[1];
  const float* g0 = (const float*)d_in[2];
  const float* b0 = (const float*)d_in[3];
  const float* W1 = (const float*)d_in[4];
  const float* g1 = (const float*)d_in[5];
  const float* b1 = (const float*)d_in[6];
  const float* W2 = (const float*)d_in[7];
  const float* g2 = (const float*)d_in[8];
  const float* b2 = (const float*)d_in[9];
  const float* W3 = (const float*)d_in[10];
  const float* g3 = (const float*)d_in[11];
  const float* b3 = (const float*)d_in[12];

  float* ws  = (float*)d_ws;
  float* u   = ws;                               // 16*1024*256
  float* w   = u  + (size_t)B_ * N_ * 256;
  float* Mx  = w  + (size_t)B_ * N_ * 256;
  float* Mn  = Mx + (size_t)B_ * N_ * 256;
  float* h0b = Mn + (size_t)B_ * N_ * 256;       // (B,<=128,N) ping
  float* h1b = h0b + (size_t)B_ * 128 * N_;      // pong
  float* xxv = h1b + (size_t)B_ * 128 * N_;      // B*N norms
  int*   idx = (int*)(xxv + B_ * N_);            // B*N*K
  double* stats = (double*)(idx + (size_t)B_ * N_ * K_);  // 4 * 512 doubles

  zero_stats<<<8, 256, 0, stream>>>(stats);

  // Layer 0: C=4, CO=64
  xx_kernel<4><<<B_ * N_ / 256, 256, 0, stream>>>(x, xxv);
  knn_kernel<4><<<dim3(64, B_), 256, 0, stream>>>(x, xxv, idx);
  gemm_uw_kernel<4, 64><<<dim3(8, 2, B_), 256, 0, stream>>>(x, W0, u, w);
  passA_kernel<64, 8><<<dim3(16, B_), 256, 0, stream>>>(u, w, idx, Mx, Mn, stats);
  passB_kernel<64><<<dim3(16, B_), 256, 0, stream>>>(Mx, Mn, w, stats, g0, b0, h0b);

  // Layer 1: C=64, CO=64
  xx_kernel<64><<<B_ * N_ / 256, 256, 0, stream>>>(h0b, xxv);
  knn_kernel<64><<<dim3(64, B_), 256, 0, stream>>>(h0b, xxv, idx);
  gemm_uw_kernel<64, 64><<<dim3(8, 2, B_), 256, 0, stream>>>(h0b, W1, u, w);
  passA_kernel<64, 8><<<dim3(16, B_), 256, 0, stream>>>(u, w, idx, Mx, Mn, stats + 512);
  passB_kernel<64><<<dim3(16, B_), 256, 0, stream>>>(Mx, Mn, w, stats + 512, g1, b1, h1b);

  // Layer 2: C=64, CO=128
  xx_kernel<64><<<B_ * N_ / 256, 256, 0, stream>>>(h1b, xxv);
  knn_kernel<64><<<dim3(64, B_), 256, 0, stream>>>(h1b, xxv, idx);
  gemm_uw_kernel<64, 128><<<dim3(8, 4, B_), 256, 0, stream>>>(h1b, W2, u, w);
  passA_kernel<128, 4><<<dim3(16, B_), 256, 0, stream>>>(u, w, idx, Mx, Mn, stats + 1024);
  passB_kernel<128><<<dim3(16, B_), 256, 0, stream>>>(Mx, Mn, w, stats + 1024, g2, b2, h0b);

  // Layer 3: C=128, CO=256
  xx_kernel<128><<<B_ * N_ / 256, 256, 0, stream>>>(h0b, xxv);
  knn_kernel<128><<<dim3(64, B_), 256, 0, stream>>>(h0b, xxv, idx);
  gemm_uw_kernel<128, 256><<<dim3(8, 8, B_), 256, 0, stream>>>(h0b, W3, u, w);
  passA_kernel<256, 2><<<dim3(16, B_), 256, 0, stream>>>(u, w, idx, Mx, Mn, stats + 1536);
  final_kernel<<<B_, 256, 0, stream>>>(Mx, Mn, w, stats + 1536, g3, b3, (float*)d_out);
}

// Round 6
// 1426.817 us; speedup vs baseline: 1.0212x; 1.0212x over previous
//
#include <hip/hip_runtime.h>
#include <math.h>

static constexpr int B_ = 16;
static constexpr int N_ = 1024;
static constexpr int K_ = 20;

// ---------------- per-point squared norm ----------------
template<int C>
__global__ __launch_bounds__(256) void xx_kernel(const float* __restrict__ h,
                                                 float* __restrict__ xx) {
  int i = blockIdx.x * 256 + threadIdx.x;
  if (i >= B_ * N_) return;
  int b = i >> 10, n = i & 1023;
  const float* hb = h + (size_t)b * C * N_ + n;
  float s = 0.f;
  #pragma unroll 4
  for (int c = 0; c < C; ++c) { float v = hb[(size_t)c * N_]; s = fmaf(v, v, s); }
  xx[i] = s;
}

// ---------------- fused distance + top-20 selection (register-resident) -------
// block = (b, 16 rows), 4 waves x 4 rows/wave. Lane holds 16 distance values
// per row (col = ch*128 + 2*lane + j). Selection: per-lane bitonic sort once,
// then 10 rounds; each round's 6-step butterfly carries a sorted top-2 pair
// (pops 2 winners/round). 4 rows' chains are independent -> ILP hides shuffle
// latency. All private-array indices compile-time static (rule #20).
// Pop = full predicated shift + sentinel backfill (R4 bug: truncated shifts
// without backfill created in-window duplicates when a lane popped 2/round).
template<int C>
__global__ __launch_bounds__(256) void knn_kernel(const float* __restrict__ h,
                                                  const float* __restrict__ xx,
                                                  int* __restrict__ idxg) {
  constexpr int CC = (C < 64) ? C : 64;
  __shared__ float xm_s[CC][128];      // <= 32 KB
  __shared__ float xn_s[C][16];        // <= 8 KB
  const int b  = blockIdx.y;
  const int n0 = blockIdx.x * 16;
  const int tid = threadIdx.x;
  const int lane = tid & 63;
  const int wv   = tid >> 6;
  const int rb   = wv * 4;
  const float* hb = h + (size_t)b * C * N_;
  const float* xxb = xx + b * N_;

  for (int i = tid; i < C * 16; i += 256) {
    int c = i >> 4, r = i & 15;
    xn_s[c][r] = hb[(size_t)c * N_ + n0 + r];
  }
  float xxn[4];
  #pragma unroll
  for (int rr = 0; rr < 4; ++rr) xxn[rr] = xxb[n0 + rb + rr];

  float val[4][16];   // val[row][t], t = 2*ch + j, col = ch*128 + 2*lane + j
  #pragma unroll
  for (int ch = 0; ch < 8; ++ch) {          // fully unrolled: static val indices
    const int m0 = ch * 128;
    float acc0[4] = {0.f, 0.f, 0.f, 0.f};
    float acc1[4] = {0.f, 0.f, 0.f, 0.f};
    #pragma unroll
    for (int cc0 = 0; cc0 < C; cc0 += CC) {
      __syncthreads();                       // protect previous chunk reads (+xn on first)
      #pragma unroll 4
      for (int i = tid; i < CC * 128; i += 256) {
        int c = i >> 7, mm = i & 127;
        xm_s[c][mm] = hb[(size_t)(cc0 + c) * N_ + m0 + mm];
      }
      __syncthreads();
      #pragma unroll 4
      for (int c = 0; c < CC; ++c) {
        float2 xm2 = *(const float2*)&xm_s[c][2 * lane];          // ds_read_b64
        float4 xn4 = *(const float4*)&xn_s[cc0 + c][rb];          // broadcast b128
        float xnv[4] = {xn4.x, xn4.y, xn4.z, xn4.w};
        #pragma unroll
        for (int rr = 0; rr < 4; ++rr) {
          acc0[rr] = fmaf(xnv[rr], xm2.x, acc0[rr]);
          acc1[rr] = fmaf(xnv[rr], xm2.y, acc1[rr]);
        }
      }
    }
    // neg_d2 = -((xx_n - 2*inner) + xx_m)  (same fp32 rounding as reference path)
    float2 xxm2 = *(const float2*)&xxb[m0 + 2 * lane];
    #pragma unroll
    for (int rr = 0; rr < 4; ++rr) {
      val[rr][2 * ch]     = -(fmaf(-2.f, acc0[rr], xxn[rr]) + xxm2.x);
      val[rr][2 * ch + 1] = -(fmaf(-2.f, acc1[rr], xxn[rr]) + xxm2.y);
    }
  }

  // -------- selection --------
  unsigned col_[4][16];
  #pragma unroll
  for (int r = 0; r < 4; ++r) {
    #pragma unroll
    for (int t = 0; t < 16; ++t)
      col_[r][t] = (unsigned)((t >> 1) * 128 + 2 * lane + (t & 1));
    // bitonic sort, descending by (value, then lowest col on ties)
    #pragma unroll
    for (int k = 2; k <= 16; k <<= 1) {
      #pragma unroll
      for (int j = k >> 1; j > 0; j >>= 1) {
        #pragma unroll
        for (int i = 0; i < 16; ++i) {
          int l = i ^ j;
          if (l > i) {
            bool up = (i & k) == 0;
            bool gt = (val[r][l] > val[r][i]) ||
                      (val[r][l] == val[r][i] && col_[r][l] < col_[r][i]);
            bool cnd = up ? gt : !gt;
            float tv = val[r][i]; unsigned tc = col_[r][i];
            val[r][i] = cnd ? val[r][l] : tv;   col_[r][i] = cnd ? col_[r][l] : tc;
            val[r][l] = cnd ? tv : val[r][l];   col_[r][l] = cnd ? tc : col_[r][l];
          }
        }
      }
    }
  }

  const int outbase = (b * N_ + n0 + rb) * K_;
  #pragma unroll 1
  for (int it = 0; it < K_ / 2; ++it) {
    #pragma unroll
    for (int r = 0; r < 4; ++r) {
      float    a0v = val[r][0], a1v = val[r][1];
      unsigned a0c = col_[r][0], a1c = col_[r][1];
      #pragma unroll
      for (int off = 32; off >= 1; off >>= 1) {
        float    b0v = __shfl_xor(a0v, off);
        int      b0c = __shfl_xor((int)a0c, off);
        float    b1v = __shfl_xor(a1v, off);
        int      b1c = __shfl_xor((int)a1c, off);
        bool aw = (a0v > b0v) || (a0v == b0v && a0c < (unsigned)b0c);
        bool w1 = (a1v > b0v) || (a1v == b0v && a1c < (unsigned)b0c);
        bool w2 = (a0v > b1v) || (a0v == b1v && a0c < (unsigned)b1c);
        float    m1v = w1 ? a1v : b0v;  unsigned m1c = w1 ? a1c : (unsigned)b0c;
        float    m2v = w2 ? a0v : b1v;  unsigned m2c = w2 ? a0c : (unsigned)b1c;
        a0v = aw ? a0v : b0v;  a0c = aw ? a0c : (unsigned)b0c;
        a1v = aw ? m1v : m2v;  a1c = aw ? m1c : m2c;
      }
      if (lane == 0) {
        idxg[outbase + r * K_ + 2 * it]     = (int)a0c;
        idxg[outbase + r * K_ + 2 * it + 1] = (int)a1c;
      }
      if (it < K_ / 2 - 1) {
        // pop up to 2 winners from this lane's head: full predicated shift
        // with sentinel backfill (sentinels can never be selected).
        bool hit0 = (col_[r][0] == a0c) || (col_[r][0] == a1c);
        #pragma unroll
        for (int t = 0; t < 15; ++t) {
          val[r][t]  = hit0 ? val[r][t + 1]  : val[r][t];
          col_[r][t] = hit0 ? col_[r][t + 1] : col_[r][t];
        }
        val[r][15]  = hit0 ? -3.4e38f     : val[r][15];
        col_[r][15] = hit0 ? 0xFFFFFFFFu  : col_[r][15];
        bool hit1 = (col_[r][0] == a1c);
        #pragma unroll
        for (int t = 0; t < 15; ++t) {
          val[r][t]  = hit1 ? val[r][t + 1]  : val[r][t];
          col_[r][t] = hit1 ? col_[r][t + 1] : col_[r][t];
        }
        val[r][15]  = hit1 ? -3.4e38f     : val[r][15];
        col_[r][15] = hit1 ? 0xFFFFFFFFu  : col_[r][15];
      }
    }
  }
}

// ---------------- u = W1*h, w = (W2-W1)*h ----------------
// out layout (B, N, CO). grid: x = N/128, y = (CO/64)*2 (even=u, odd=w), z = B
template<int C, int CO>
__global__ __launch_bounds__(256) void gemm_uw_kernel(const float* __restrict__ h,
    const float* __restrict__ W, float* __restrict__ ubuf, float* __restrict__ wbuf) {
  __shared__ float hs[C][128];
  __shared__ float Ws[64][C + 1];          // +1 pad: kill 32-way bank conflict
  const int b  = blockIdx.z;
  const int n0 = blockIdx.x * 128;
  const int which = blockIdx.y & 1;
  const int o0 = (blockIdx.y >> 1) * 64;
  const int tid = threadIdx.x;
  for (int i = tid; i < 64 * C; i += 256) {
    int o = i / C, c = i % C;
    const float* wr = W + (size_t)(o0 + o) * (2 * C);
    float w1 = wr[c];
    Ws[o][c] = which ? (wr[C + c] - w1) : w1;
  }
  const float* hb = h + (size_t)b * C * N_ + n0;
  for (int i = tid; i < C * 128; i += 256) {
    int c = i >> 7, nn = i & 127;
    hs[c][nn] = hb[(size_t)c * N_ + nn];
  }
  __syncthreads();
  const int ob = (tid & 15) * 4;
  const int nb = (tid >> 4) * 8;
  float acc[8][4];
  #pragma unroll
  for (int i = 0; i < 8; ++i)
    #pragma unroll
    for (int j = 0; j < 4; ++j) acc[i][j] = 0.f;
  for (int c = 0; c < C; ++c) {
    float hv[8];
    *(float4*)&hv[0] = *(const float4*)&hs[c][nb];
    *(float4*)&hv[4] = *(const float4*)&hs[c][nb + 4];
    float w0 = Ws[ob][c], w1 = Ws[ob + 1][c], w2 = Ws[ob + 2][c], w3 = Ws[ob + 3][c];
    #pragma unroll
    for (int i = 0; i < 8; ++i) {
      acc[i][0] = fmaf(hv[i], w0, acc[i][0]);
      acc[i][1] = fmaf(hv[i], w1, acc[i][1]);
      acc[i][2] = fmaf(hv[i], w2, acc[i][2]);
      acc[i][3] = fmaf(hv[i], w3, acc[i][3]);
    }
  }
  float* out = (which ? wbuf : ubuf) + ((size_t)(b * N_ + n0 + nb)) * CO + o0 + ob;
  #pragma unroll
  for (int i = 0; i < 8; ++i) {
    float4 v4; v4.x = acc[i][0]; v4.y = acc[i][1]; v4.z = acc[i][2]; v4.w = acc[i][3];
    *(float4*)(out + (size_t)i * CO) = v4;
  }
}

// ---------------- gather pass: per-(o,n) max/min over k + fp64 stats ----------------
template<int CO, int NSPLIT>
__global__ __launch_bounds__(256) void passA_kernel(const float* __restrict__ ubuf,
    const float* __restrict__ wbuf, const int* __restrict__ idxg,
    float* __restrict__ Mx, float* __restrict__ Mn, double* __restrict__ stats) {
  __shared__ float us[N_][32];             // 128 KB, gather reads conflict-free (o fastest)
  const int b = blockIdx.y;
  const int otile = blockIdx.x / NSPLIT;
  const int ns    = blockIdx.x % NSPLIT;
  const int o0 = otile * 32;
  constexpr int NSUB = N_ / NSPLIT;
  const int nstart = ns * NSUB;
  const int tid = threadIdx.x;
  const float* ub = ubuf + (size_t)b * N_ * CO + o0;
  for (int i = tid; i < N_ * 32; i += 256) {
    int n = i >> 5, o = i & 31;
    us[n][o] = ub[(size_t)n * CO + o];
  }
  __syncthreads();
  const int o = tid & 31, ng = tid >> 5;
  double s_y = 0.0, s_y2 = 0.0;
  const size_t bnc = (size_t)b * N_ * CO;
  for (int n = nstart + ng; n < nstart + NSUB; n += 8) {
    const int* ip = idxg + (size_t)(b * N_ + n) * K_;
    int js[20];
    #pragma unroll
    for (int q = 0; q < 5; ++q) {
      int4 t4 = ((const int4*)ip)[q];
      js[q * 4 + 0] = t4.x; js[q * 4 + 1] = t4.y;
      js[q * 4 + 2] = t4.z; js[q * 4 + 3] = t4.w;
    }
    float mx = -3.4e38f, mn = 3.4e38f, s1 = 0.f, s2 = 0.f;
    #pragma unroll
    for (int k = 0; k < 20; ++k) {
      float v = us[js[k]][o];
      mx = fmaxf(mx, v); mn = fminf(mn, v);
      s1 += v; s2 = fmaf(v, v, s2);
    }
    float wvv = wbuf[bnc + (size_t)n * CO + o0 + o];
    s_y  += (double)s1 + 20.0 * (double)wvv;
    s_y2 += (double)s2 + 2.0 * (double)wvv * (double)s1 + 20.0 * (double)wvv * (double)wvv;
    Mx[bnc + (size_t)n * CO + o0 + o] = mx;
    Mn[bnc + (size_t)n * CO + o0 + o] = mn;
  }
  __syncthreads();                          // us dead: reuse as reduction scratch
  double* sc = (double*)&us[0][0];
  sc[(o * 8 + ng) * 2]     = s_y;
  sc[(o * 8 + ng) * 2 + 1] = s_y2;
  __syncthreads();
  if (tid < 32) {
    double a = 0.0, c2 = 0.0;
    #pragma unroll
    for (int g = 0; g < 8; ++g) { a += sc[(tid * 8 + g) * 2]; c2 += sc[(tid * 8 + g) * 2 + 1]; }
    atomicAdd(&stats[(o0 + tid) * 2],     a);
    atomicAdd(&stats[(o0 + tid) * 2 + 1], c2);
  }
}

// ---------------- BN + LeakyReLU + (implicit max_k) + transpose to (B,C,N) ----------------
template<int CO>
__global__ __launch_bounds__(256) void passB_kernel(const float* __restrict__ Mx,
    const float* __restrict__ Mn, const float* __restrict__ wbuf,
    const double* __restrict__ stats, const float* __restrict__ gam,
    const float* __restrict__ bet, float* __restrict__ hout) {
  __shared__ float T[CO][65];
  __shared__ float a_s[CO], c_s[CO];
  const int b = blockIdx.y, n0 = blockIdx.x * 64;
  const int tid = threadIdx.x;
  const double CNT = (double)B_ * N_ * K_;
  for (int oo = tid; oo < CO; oo += 256) {
    double m  = stats[oo * 2] / CNT;
    double vv = stats[oo * 2 + 1] / CNT - m * m;
    float a = gam[oo] * rsqrtf((float)vv + 1e-5f);
    a_s[oo] = a;
    c_s[oo] = bet[oo] - a * (float)m;
  }
  __syncthreads();
  const size_t base = (size_t)(b * N_ + n0) * CO;
  for (int i = tid; i < 64 * CO; i += 256) {
    int nn = i / CO, oo = i % CO;
    float a = a_s[oo];
    size_t off = base + (size_t)nn * CO + oo;
    float selv = (a >= 0.f) ? Mx[off] : Mn[off];    // max_k commutes through monotone BN+LReLU
    float z = fmaf(a, selv + wbuf[off], c_s[oo]);
    T[oo][nn] = (z >= 0.f) ? z : 0.2f * z;
  }
  __syncthreads();
  float* hb = hout + (size_t)b * CO * N_ + n0;
  for (int i = tid; i < 64 * CO; i += 256) {
    int oo = i >> 6, nn = i & 63;
    hb[(size_t)oo * N_ + nn] = T[oo][nn];
  }
}

// ---------------- final layer: BN + LReLU + max over (n,k) ----------------
__global__ __launch_bounds__(256) void final_kernel(const float* __restrict__ Mx,
    const float* __restrict__ Mn, const float* __restrict__ wbuf,
    const double* __restrict__ stats, const float* __restrict__ gam,
    const float* __restrict__ bet, float* __restrict__ out) {
  const int b = blockIdx.x, o = threadIdx.x;   // 256 threads = CO
  const double CNT = (double)B_ * N_ * K_;
  double m  = stats[o * 2] / CNT;
  double vv = stats[o * 2 + 1] / CNT - m * m;
  float a = gam[o] * rsqrtf((float)vv + 1e-5f);
  float c = bet[o] - a * (float)m;
  const float* mp = ((a >= 0.f) ? Mx : Mn) + (size_t)b * N_ * 256 + o;
  const float* wp = wbuf + (size_t)b * N_ * 256 + o;
  float best = -3.4e38f;
  for (int n = 0; n < N_; ++n) {
    float z = fmaf(a, mp[(size_t)n * 256] + wp[(size_t)n * 256], c);
    z = (z >= 0.f) ? z : 0.2f * z;
    best = fmaxf(best, z);
  }
  out[b * 256 + o] = best;
}

__global__ void zero_stats(double* p) {
  int i = blockIdx.x * 256 + threadIdx.x;
  if (i < 2048) p[i] = 0.0;
}

extern "C" void kernel_launch(void* const* d_in, const int* in_sizes, int n_in,
                              void* d_out, int out_size, void* d_ws, size_t ws_size,
                              hipStream_t stream) {
  (void)in_sizes; (void)n_in; (void)out_size; (void)ws_size;
  const float* x  = (const float*)d_in[0];
  const float* W0 = (const float*)d_in[1];
  const float* g0 = (const float*)d_in[2];
  const float* b0 = (const float*)d_in[3];
  const float* W1 = (const float*)d_in[4];
  const float* g1 = (const float*)d_in[5];
  const float* b1 = (const float*)d_in[6];
  const float* W2 = (const float*)d_in[7];
  const float* g2 = (const float*)d_in[8];
  const float* b2 = (const float*)d_in[9];
  const float* W3 = (const float*)d_in[10];
  const float* g3 = (const float*)d_in[11];
  const float* b3 = (const float*)d_in[12];

  float* ws  = (float*)d_ws;
  float* u   = ws;                               // 16*1024*256
  float* w   = u  + (size_t)B_ * N_ * 256;
  float* Mx  = w  + (size_t)B_ * N_ * 256;
  float* Mn  = Mx + (size_t)B_ * N_ * 256;
  float* h0b = Mn + (size_t)B_ * N_ * 256;       // (B,<=128,N) ping
  float* h1b = h0b + (size_t)B_ * 128 * N_;      // pong
  float* xxv = h1b + (size_t)B_ * 128 * N_;      // B*N norms
  int*   idx = (int*)(xxv + B_ * N_);            // B*N*K
  double* stats = (double*)(idx + (size_t)B_ * N_ * K_);  // 4 * 512 doubles

  zero_stats<<<8, 256, 0, stream>>>(stats);

  // Layer 0: C=4, CO=64
  xx_kernel<4><<<B_ * N_ / 256, 256, 0, stream>>>(x, xxv);
  knn_kernel<4><<<dim3(64, B_), 256, 0, stream>>>(x, xxv, idx);
  gemm_uw_kernel<4, 64><<<dim3(8, 2, B_), 256, 0, stream>>>(x, W0, u, w);
  passA_kernel<64, 8><<<dim3(16, B_), 256, 0, stream>>>(u, w, idx, Mx, Mn, stats);
  passB_kernel<64><<<dim3(16, B_), 256, 0, stream>>>(Mx, Mn, w, stats, g0, b0, h0b);

  // Layer 1: C=64, CO=64
  xx_kernel<64><<<B_ * N_ / 256, 256, 0, stream>>>(h0b, xxv);
  knn_kernel<64><<<dim3(64, B_), 256, 0, stream>>>(h0b, xxv, idx);
  gemm_uw_kernel<64, 64><<<dim3(8, 2, B_), 256, 0, stream>>>(h0b, W1, u, w);
  passA_kernel<64, 8><<<dim3(16, B_), 256, 0, stream>>>(u, w, idx, Mx, Mn, stats + 512);
  passB_kernel<64><<<dim3(16, B_), 256, 0, stream>>>(Mx, Mn, w, stats + 512, g1, b1, h1b);

  // Layer 2: C=64, CO=128
  xx_kernel<64><<<B_ * N_ / 256, 256, 0, stream>>>(h1b, xxv);
  knn_kernel<64><<<dim3(64, B_), 256, 0, stream>>>(h1b, xxv, idx);
  gemm_uw_kernel<64, 128><<<dim3(8, 4, B_), 256, 0, stream>>>(h1b, W2, u, w);
  passA_kernel<128, 4><<<dim3(16, B_), 256, 0, stream>>>(u, w, idx, Mx, Mn, stats + 1024);
  passB_kernel<128><<<dim3(16, B_), 256, 0, stream>>>(Mx, Mn, w, stats + 1024, g2, b2, h0b);

  // Layer 3: C=128, CO=256
  xx_kernel<128><<<B_ * N_ / 256, 256, 0, stream>>>(h0b, xxv);
  knn_kernel<128><<<dim3(64, B_), 256, 0, stream>>>(h0b, xxv, idx);
  gemm_uw_kernel<128, 256><<<dim3(8, 8, B_), 256, 0, stream>>>(h0b, W3, u, w);
  passA_kernel<256, 2><<<dim3(16, B_), 256, 0, stream>>>(u, w, idx, Mx, Mn, stats + 1536);
  final_kernel<<<B_, 256, 0, stream>>>(Mx, Mn, w, stats + 1536, g3, b3, (float*)d_out);
}

// Round 8
// 1405.092 us; speedup vs baseline: 1.0369x; 1.0155x over previous
//
#include <hip/hip_runtime.h>
#include <math.h>

static constexpr int B_ = 16;
static constexpr int N_ = 1024;
static constexpr int K_ = 20;

__device__ __forceinline__ unsigned long long shflx64(unsigned long long x, int m) {
  int lo = __shfl_xor((int)(unsigned)x, m);
  int hi = __shfl_xor((int)(unsigned)(x >> 32), m);
  return ((unsigned long long)(unsigned)hi << 32) | (unsigned)lo;
}

// descending CE: keep larger at index a
#define CED(X, a, b) { bool sw_ = X[a] < X[b];                         \
    unsigned long long t_ = X[a];                                      \
    X[a] = sw_ ? X[b] : t_; X[b] = sw_ ? t_ : X[b]; }

// One butterfly level: fetch partner's sorted-20 (S untouched -> shfl-safe),
// half-clean T[i]=max(S[i],P[19-i]) (= top-20 of union, valley-bitonic),
// then 40-CE resort (= 32-wide bitonic merge with +inf FRONT pads, nops
// removed; R7 bug was -inf TAIL pads, which is not bitonic).
#define MERGE_LEVEL(S, D, M, DO_NET)                                   \
  {                                                                    \
    _Pragma("unroll")                                                  \
    for (int i_ = 0; i_ < 20; ++i_) {                                  \
      unsigned long long p_ = shflx64(S[19 - i_], (M));                \
      D[i_] = (S[i_] > p_) ? S[i_] : p_;                               \
    }                                                                  \
    if (DO_NET) {                                                      \
      CED(D,0,16) CED(D,1,17) CED(D,2,18) CED(D,3,19)                  \
      CED(D,4,12) CED(D,5,13) CED(D,6,14) CED(D,7,15)                  \
      CED(D,8,16) CED(D,9,17) CED(D,10,18) CED(D,11,19)                \
      CED(D,4,8)  CED(D,5,9)  CED(D,6,10) CED(D,7,11)                  \
      CED(D,12,16) CED(D,13,17) CED(D,14,18) CED(D,15,19)              \
      CED(D,0,2)  CED(D,1,3)  CED(D,4,6)  CED(D,5,7)                   \
      CED(D,8,10) CED(D,9,11) CED(D,12,14) CED(D,13,15)                \
      CED(D,16,18) CED(D,17,19)                                        \
      CED(D,0,1)  CED(D,2,3)  CED(D,4,5)  CED(D,6,7)                   \
      CED(D,8,9)  CED(D,10,11) CED(D,12,13) CED(D,14,15)               \
      CED(D,16,17) CED(D,18,19)                                        \
    }                                                                  \
  }

// ---------------- per-point squared norm ----------------
template<int C>
__global__ __launch_bounds__(256) void xx_kernel(const float* __restrict__ h,
                                                 float* __restrict__ xx) {
  int i = blockIdx.x * 256 + threadIdx.x;
  if (i >= B_ * N_) return;
  int b = i >> 10, n = i & 1023;
  const float* hb = h + (size_t)b * C * N_ + n;
  float s = 0.f;
  #pragma unroll 4
  for (int c = 0; c < C; ++c) { float v = hb[(size_t)c * N_]; s = fmaf(v, v, s); }
  xx[i] = s;
}

// ---------------- fused distance + top-20 selection (merge-tree v2) ----------
// block = (b, 16 rows), 8 waves x 2 rows/wave (512 thr). Lane holds 16
// distances/row (col = ch*128 + 2*lane + j). Per row: pack u64 keys
// (sortable(val)<<32 | ~col) -> ties impossible, tie-break == top_k lowest-
// index; bitonic sort-16 desc + 4 zero-pads; 6 butterfly levels (hypercube
// all-reduce) of MERGE_LEVEL; last level skips resort (set suffices —
// downstream passA is order-invariant). Rows sequential (sched_barrier)
// to cap VGPR. All private indices compile-time static (rule #20).
template<int C>
__global__ __launch_bounds__(512) void knn_kernel(const float* __restrict__ h,
                                                  const float* __restrict__ xx,
                                                  int* __restrict__ idxg) {
  constexpr int CC = (C < 64) ? C : 64;
  __shared__ float xm_s[CC][128];      // <= 32 KB
  __shared__ float xn_s[C][16];        // <= 8 KB
  const int b  = blockIdx.y;
  const int n0 = blockIdx.x * 16;
  const int tid = threadIdx.x;
  const int lane = tid & 63;
  const int wv   = tid >> 6;           // 0..7
  const int rb   = wv * 2;             // 2 rows per wave
  const float* hb = h + (size_t)b * C * N_;
  const float* xxb = xx + b * N_;

  for (int i = tid; i < C * 16; i += 512) {
    int c = i >> 4, r = i & 15;
    xn_s[c][r] = hb[(size_t)c * N_ + n0 + r];
  }
  float xxn[2];
  #pragma unroll
  for (int rr = 0; rr < 2; ++rr) xxn[rr] = xxb[n0 + rb + rr];

  float val[2][16];   // val[row][t], t = 2*ch + j, col = ch*128 + 2*lane + j
  #pragma unroll
  for (int ch = 0; ch < 8; ++ch) {          // fully unrolled: static val indices
    const int m0 = ch * 128;
    float acc0[2] = {0.f, 0.f};
    float acc1[2] = {0.f, 0.f};
    #pragma unroll
    for (int cc0 = 0; cc0 < C; cc0 += CC) {
      __syncthreads();                       // protect previous chunk reads (+xn on first)
      #pragma unroll 4
      for (int i = tid; i < CC * 128; i += 512) {
        int c = i >> 7, mm = i & 127;
        xm_s[c][mm] = hb[(size_t)(cc0 + c) * N_ + m0 + mm];
      }
      __syncthreads();
      #pragma unroll 4
      for (int c = 0; c < CC; ++c) {
        float2 xm2 = *(const float2*)&xm_s[c][2 * lane];          // ds_read_b64
        float2 xn2 = *(const float2*)&xn_s[cc0 + c][rb];          // broadcast
        acc0[0] = fmaf(xn2.x, xm2.x, acc0[0]);
        acc1[0] = fmaf(xn2.x, xm2.y, acc1[0]);
        acc0[1] = fmaf(xn2.y, xm2.x, acc0[1]);
        acc1[1] = fmaf(xn2.y, xm2.y, acc1[1]);
      }
    }
    // neg_d2 = -((xx_n - 2*inner) + xx_m)  (same fp32 rounding as reference path)
    float2 xxm2 = *(const float2*)&xxb[m0 + 2 * lane];
    #pragma unroll
    for (int rr = 0; rr < 2; ++rr) {
      val[rr][2 * ch]     = -(fmaf(-2.f, acc0[rr], xxn[rr]) + xxm2.x);
      val[rr][2 * ch + 1] = -(fmaf(-2.f, acc1[rr], xxn[rr]) + xxm2.y);
    }
  }

  // -------- selection: merge-tree per row (rows sequential for VGPR) --------
  #pragma unroll
  for (int r = 0; r < 2; ++r) {
    unsigned long long La[20], Lb[20];
    #pragma unroll
    for (int t = 0; t < 16; ++t) {
      float v = val[r][t] + 0.0f;                 // canonicalize -0.0 -> +0.0
      unsigned vb = __float_as_uint(v);
      unsigned s  = vb ^ (unsigned)(((int)vb >> 31) | 0x80000000);
      unsigned col = (unsigned)((t >> 1) * 128 + 2 * lane + (t & 1));
      La[t] = ((unsigned long long)s << 32) | (unsigned)(~col);
    }
    // bitonic sort La[0..15] descending (strict u64, no ties possible)
    #pragma unroll
    for (int k = 2; k <= 16; k <<= 1) {
      #pragma unroll
      for (int j = k >> 1; j > 0; j >>= 1) {
        #pragma unroll
        for (int i = 0; i < 16; ++i) {
          int l = i ^ j;
          if (l > i) {
            bool up = (i & k) == 0;
            bool gt = La[l] > La[i];
            bool sw = up ? gt : !gt;
            unsigned long long a = La[i];
            La[i] = sw ? La[l] : a;
            La[l] = sw ? a : La[l];
          }
        }
      }
    }
    La[16] = 0ull; La[17] = 0ull; La[18] = 0ull; La[19] = 0ull;  // pads < any real key

    MERGE_LEVEL(La, Lb, 1,  true)
    MERGE_LEVEL(Lb, La, 2,  true)
    MERGE_LEVEL(La, Lb, 4,  true)
    MERGE_LEVEL(Lb, La, 8,  true)
    MERGE_LEVEL(La, Lb, 16, true)
    MERGE_LEVEL(Lb, La, 32, false)   // set only; order not needed downstream

    if (lane == 0) {
      const int outbase = (b * N_ + n0 + rb + r) * K_;
      #pragma unroll
      for (int i = 0; i < 20; ++i)
        idxg[outbase + i] = (int)(~(unsigned)La[i]);
    }
    __builtin_amdgcn_sched_barrier(0);   // keep rows' lifetimes disjoint
  }
}

// ---------------- u = W1*h, w = (W2-W1)*h ----------------
// out layout (B, N, CO). grid: x = N/128, y = (CO/64)*2 (even=u, odd=w), z = B
template<int C, int CO>
__global__ __launch_bounds__(256) void gemm_uw_kernel(const float* __restrict__ h,
    const float* __restrict__ W, float* __restrict__ ubuf, float* __restrict__ wbuf) {
  __shared__ float hs[C][128];
  __shared__ float Ws[64][C + 1];          // +1 pad: kill 32-way bank conflict
  const int b  = blockIdx.z;
  const int n0 = blockIdx.x * 128;
  const int which = blockIdx.y & 1;
  const int o0 = (blockIdx.y >> 1) * 64;
  const int tid = threadIdx.x;
  for (int i = tid; i < 64 * C; i += 256) {
    int o = i / C, c = i % C;
    const float* wr = W + (size_t)(o0 + o) * (2 * C);
    float w1 = wr[c];
    Ws[o][c] = which ? (wr[C + c] - w1) : w1;
  }
  const float* hb = h + (size_t)b * C * N_ + n0;
  for (int i = tid; i < C * 128; i += 256) {
    int c = i >> 7, nn = i & 127;
    hs[c][nn] = hb[(size_t)c * N_ + nn];
  }
  __syncthreads();
  const int ob = (tid & 15) * 4;
  const int nb = (tid >> 4) * 8;
  float acc[8][4];
  #pragma unroll
  for (int i = 0; i < 8; ++i)
    #pragma unroll
    for (int j = 0; j < 4; ++j) acc[i][j] = 0.f;
  for (int c = 0; c < C; ++c) {
    float hv[8];
    *(float4*)&hv[0] = *(const float4*)&hs[c][nb];
    *(float4*)&hv[4] = *(const float4*)&hs[c][nb + 4];
    float w0 = Ws[ob][c], w1 = Ws[ob + 1][c], w2 = Ws[ob + 2][c], w3 = Ws[ob + 3][c];
    #pragma unroll
    for (int i = 0; i < 8; ++i) {
      acc[i][0] = fmaf(hv[i], w0, acc[i][0]);
      acc[i][1] = fmaf(hv[i], w1, acc[i][1]);
      acc[i][2] = fmaf(hv[i], w2, acc[i][2]);
      acc[i][3] = fmaf(hv[i], w3, acc[i][3]);
    }
  }
  float* out = (which ? wbuf : ubuf) + ((size_t)(b * N_ + n0 + nb)) * CO + o0 + ob;
  #pragma unroll
  for (int i = 0; i < 8; ++i) {
    float4 v4; v4.x = acc[i][0]; v4.y = acc[i][1]; v4.z = acc[i][2]; v4.w = acc[i][3];
    *(float4*)(out + (size_t)i * CO) = v4;
  }
}

// ---------------- gather pass: per-(o,n) max/min over k + fp64 stats ----------------
template<int CO, int NSPLIT>
__global__ __launch_bounds__(256) void passA_kernel(const float* __restrict__ ubuf,
    const float* __restrict__ wbuf, const int* __restrict__ idxg,
    float* __restrict__ Mx, float* __restrict__ Mn, double* __restrict__ stats) {
  __shared__ float us[N_][32];             // 128 KB, gather reads conflict-free (o fastest)
  const int b = blockIdx.y;
  const int otile = blockIdx.x / NSPLIT;
  const int ns    = blockIdx.x % NSPLIT;
  const int o0 = otile * 32;
  constexpr int NSUB = N_ / NSPLIT;
  const int nstart = ns * NSUB;
  const int tid = threadIdx.x;
  const float* ub = ubuf + (size_t)b * N_ * CO + o0;
  for (int i = tid; i < N_ * 32; i += 256) {
    int n = i >> 5, o = i & 31;
    us[n][o] = ub[(size_t)n * CO + o];
  }
  __syncthreads();
  const int o = tid & 31, ng = tid >> 5;
  double s_y = 0.0, s_y2 = 0.0;
  const size_t bnc = (size_t)b * N_ * CO;
  for (int n = nstart + ng; n < nstart + NSUB; n += 8) {
    const int* ip = idxg + (size_t)(b * N_ + n) * K_;
    int js[20];
    #pragma unroll
    for (int q = 0; q < 5; ++q) {
      int4 t4 = ((const int4*)ip)[q];
      js[q * 4 + 0] = t4.x; js[q * 4 + 1] = t4.y;
      js[q * 4 + 2] = t4.z; js[q * 4 + 3] = t4.w;
    }
    float mx = -3.4e38f, mn = 3.4e38f, s1 = 0.f, s2 = 0.f;
    #pragma unroll
    for (int k = 0; k < 20; ++k) {
      float v = us[js[k]][o];
      mx = fmaxf(mx, v); mn = fminf(mn, v);
      s1 += v; s2 = fmaf(v, v, s2);
    }
    float wvv = wbuf[bnc + (size_t)n * CO + o0 + o];
    s_y  += (double)s1 + 20.0 * (double)wvv;
    s_y2 += (double)s2 + 2.0 * (double)wvv * (double)s1 + 20.0 * (double)wvv * (double)wvv;
    Mx[bnc + (size_t)n * CO + o0 + o] = mx;
    Mn[bnc + (size_t)n * CO + o0 + o] = mn;
  }
  __syncthreads();                          // us dead: reuse as reduction scratch
  double* sc = (double*)&us[0][0];
  sc[(o * 8 + ng) * 2]     = s_y;
  sc[(o * 8 + ng) * 2 + 1] = s_y2;
  __syncthreads();
  if (tid < 32) {
    double a = 0.0, c2 = 0.0;
    #pragma unroll
    for (int g = 0; g < 8; ++g) { a += sc[(tid * 8 + g) * 2]; c2 += sc[(tid * 8 + g) * 2 + 1]; }
    atomicAdd(&stats[(o0 + tid) * 2],     a);
    atomicAdd(&stats[(o0 + tid) * 2 + 1], c2);
  }
}

// ---------------- BN + LeakyReLU + (implicit max_k) + transpose to (B,C,N) ----------------
template<int CO>
__global__ __launch_bounds__(256) void passB_kernel(const float* __restrict__ Mx,
    const float* __restrict__ Mn, const float* __restrict__ wbuf,
    const double* __restrict__ stats, const float* __restrict__ gam,
    const float* __restrict__ bet, float* __restrict__ hout) {
  __shared__ float T[CO][65];
  __shared__ float a_s[CO], c_s[CO];
  const int b = blockIdx.y, n0 = blockIdx.x * 64;
  const int tid = threadIdx.x;
  const double CNT = (double)B_ * N_ * K_;
  for (int oo = tid; oo < CO; oo += 256) {
    double m  = stats[oo * 2] / CNT;
    double vv = stats[oo * 2 + 1] / CNT - m * m;
    float a = gam[oo] * rsqrtf((float)vv + 1e-5f);
    a_s[oo] = a;
    c_s[oo] = bet[oo] - a * (float)m;
  }
  __syncthreads();
  const size_t base = (size_t)(b * N_ + n0) * CO;
  for (int i = tid; i < 64 * CO; i += 256) {
    int nn = i / CO, oo = i % CO;
    float a = a_s[oo];
    size_t off = base + (size_t)nn * CO + oo;
    float selv = (a >= 0.f) ? Mx[off] : Mn[off];    // max_k commutes through monotone BN+LReLU
    float z = fmaf(a, selv + wbuf[off], c_s[oo]);
    T[oo][nn] = (z >= 0.f) ? z : 0.2f * z;
  }
  __syncthreads();
  float* hb = hout + (size_t)b * CO * N_ + n0;
  for (int i = tid; i < 64 * CO; i += 256) {
    int oo = i >> 6, nn = i & 63;
    hb[(size_t)oo * N_ + nn] = T[oo][nn];
  }
}

// ---------------- final layer: BN + LReLU + max over (n,k) ----------------
__global__ __launch_bounds__(256) void final_kernel(const float* __restrict__ Mx,
    const float* __restrict__ Mn, const float* __restrict__ wbuf,
    const double* __restrict__ stats, const float* __restrict__ gam,
    const float* __restrict__ bet, float* __restrict__ out) {
  const int b = blockIdx.x, o = threadIdx.x;   // 256 threads = CO
  const double CNT = (double)B_ * N_ * K_;
  double m  = stats[o * 2] / CNT;
  double vv = stats[o * 2 + 1] / CNT - m * m;
  float a = gam[o] * rsqrtf((float)vv + 1e-5f);
  float c = bet[o] - a * (float)m;
  const float* mp = ((a >= 0.f) ? Mx : Mn) + (size_t)b * N_ * 256 + o;
  const float* wp = wbuf + (size_t)b * N_ * 256 + o;
  float best = -3.4e38f;
  for (int n = 0; n < N_; ++n) {
    float z = fmaf(a, mp[(size_t)n * 256] + wp[(size_t)n * 256], c);
    z = (z >= 0.f) ? z : 0.2f * z;
    best = fmaxf(best, z);
  }
  out[b * 256 + o] = best;
}

__global__ void zero_stats(double* p) {
  int i = blockIdx.x * 256 + threadIdx.x;
  if (i < 2048) p[i] = 0.0;
}

extern "C" void kernel_launch(void* const* d_in, const int* in_sizes, int n_in,
                              void* d_out, int out_size, void* d_ws, size_t ws_size,
                              hipStream_t stream) {
  (void)in_sizes; (void)n_in; (void)out_size; (void)ws_size;
  const float* x  = (const float*)d_in[0];
  const float* W0 = (const float*)d_in[1];
  const float* g0 = (const float*)d_in[2];
  const float* b0 = (const float*)d_in[3];
  const float* W1 = (const float*)d_in[4];
  const float* g1 = (const float*)d_in[5];
  const float* b1 = (const float*)d_in[6];
  const float* W2 = (const float*)d_in[7];
  const float* g2 = (const float*)d_in[8];
  const float* b2 = (const float*)d_in[9];
  const float* W3 = (const float*)d_in[10];
  const float* g3 = (const float*)d_in[11];
  const float* b3 = (const float*)d_in[12];

  float* ws  = (float*)d_ws;
  float* u   = ws;                               // 16*1024*256
  float* w   = u  + (size_t)B_ * N_ * 256;
  float* Mx  = w  + (size_t)B_ * N_ * 256;
  float* Mn  = Mx + (size_t)B_ * N_ * 256;
  float* h0b = Mn + (size_t)B_ * N_ * 256;       // (B,<=128,N) ping
  float* h1b = h0b + (size_t)B_ * 128 * N_;      // pong
  float* xxv = h1b + (size_t)B_ * 128 * N_;      // B*N norms
  int*   idx = (int*)(xxv + B_ * N_);            // B*N*K
  double* stats = (double*)(idx + (size_t)B_ * N_ * K_);  // 4 * 512 doubles

  zero_stats<<<8, 256, 0, stream>>>(stats);

  // Layer 0: C=4, CO=64
  xx_kernel<4><<<B_ * N_ / 256, 256, 0, stream>>>(x, xxv);
  knn_kernel<4><<<dim3(64, B_), 512, 0, stream>>>(x, xxv, idx);
  gemm_uw_kernel<4, 64><<<dim3(8, 2, B_), 256, 0, stream>>>(x, W0, u, w);
  passA_kernel<64, 8><<<dim3(16, B_), 256, 0, stream>>>(u, w, idx, Mx, Mn, stats);
  passB_kernel<64><<<dim3(16, B_), 256, 0, stream>>>(Mx, Mn, w, stats, g0, b0, h0b);

  // Layer 1: C=64, CO=64
  xx_kernel<64><<<B_ * N_ / 256, 256, 0, stream>>>(h0b, xxv);
  knn_kernel<64><<<dim3(64, B_), 512, 0, stream>>>(h0b, xxv, idx);
  gemm_uw_kernel<64, 64><<<dim3(8, 2, B_), 256, 0, stream>>>(h0b, W1, u, w);
  passA_kernel<64, 8><<<dim3(16, B_), 256, 0, stream>>>(u, w, idx, Mx, Mn, stats + 512);
  passB_kernel<64><<<dim3(16, B_), 256, 0, stream>>>(Mx, Mn, w, stats + 512, g1, b1, h1b);

  // Layer 2: C=64, CO=128
  xx_kernel<64><<<B_ * N_ / 256, 256, 0, stream>>>(h1b, xxv);
  knn_kernel<64><<<dim3(64, B_), 512, 0, stream>>>(h1b, xxv, idx);
  gemm_uw_kernel<64, 128><<<dim3(8, 4, B_), 256, 0, stream>>>(h1b, W2, u, w);
  passA_kernel<128, 4><<<dim3(16, B_), 256, 0, stream>>>(u, w, idx, Mx, Mn, stats + 1024);
  passB_kernel<128><<<dim3(16, B_), 256, 0, stream>>>(Mx, Mn, w, stats + 1024, g2, b2, h0b);

  // Layer 3: C=128, CO=256
  xx_kernel<128><<<B_ * N_ / 256, 256, 0, stream>>>(h0b, xxv);
  knn_kernel<128><<<dim3(64, B_), 512, 0, stream>>>(h0b, xxv, idx);
  gemm_uw_kernel<128, 256><<<dim3(8, 8, B_), 256, 0, stream>>>(h0b, W3, u, w);
  passA_kernel<256, 2><<<dim3(16, B_), 256, 0, stream>>>(u, w, idx, Mx, Mn, stats + 1536);
  final_kernel<<<B_, 256, 0, stream>>>(Mx, Mn, w, stats + 1536, g3, b3, (float*)d_out);
}